// Round 5
// baseline (1104.608 us; speedup 1.0000x reference)
//
#include <hip/hip_runtime.h>
#include <hip/hip_bf16.h>

#define HDIM 96
#define TILE 128

typedef __attribute__((ext_vector_type(8))) short  short8;
typedef __attribute__((ext_vector_type(4))) short  short4v;
typedef __attribute__((ext_vector_type(4))) float  float4v;
typedef __attribute__((ext_vector_type(4))) unsigned int uint4v;

static __device__ __forceinline__ short f2bf(float f){
    __hip_bfloat16 h = __float2bfloat16(f);
    return *reinterpret_cast<short*>(&h);
}
static __device__ __forceinline__ float bf2f(short s){
    unsigned u = ((unsigned)(unsigned short)s) << 16;
    return __uint_as_float(u);
}
// fast silu: v * rcp(1+exp(-v)) — v_rcp_f32 is ~1ulp, fine at bf16 tolerance
static __device__ __forceinline__ float silu_f(float v){
    return v * __builtin_amdgcn_rcpf(1.0f + __expf(-v));
}

// ---------------- weight swizzle into MFMA A-fragment order ----------------
// frag[lane][j] = W[k0 + (lane>>4)*8 + j][nt*16 + (lane&15)]
struct SwJob { const float* src; int ck; int ks; int ksrc; };
struct SwTable { SwJob j[22]; };

__global__ __launch_bounds__(256) void swizzle_kernel(SwTable T, short* __restrict__ dst, int total){
    int gid = blockIdx.x*256 + threadIdx.x;
    if (gid >= total) return;
    int ksg = gid / 3072;
    int e   = gid % 3072;
    const float* src = T.j[0].src; int k0 = 0, ksrc = 0;
    #pragma unroll
    for (int jj = 0; jj < 22; ++jj){
        int s = T.j[jj].ck;
        if (ksg >= s && ksg < s + T.j[jj].ks){ src = T.j[jj].src; k0 = (ksg - s)*32; ksrc = T.j[jj].ksrc; }
    }
    int nt   = e >> 9;
    int rem  = e & 511;
    int lane = rem >> 3;
    int jx   = rem & 7;
    int k = k0 + ((lane >> 4) << 3) + jx;
    int f = nt*16 + (lane & 15);
    float v = (k < ksrc) ? src[(size_t)k*HDIM + f] : 0.0f;
    dst[gid] = f2bf(v);
}

// swizzle of combined [W1s | W1r] (96 x 192) per layer for the SR GEMM
__global__ __launch_bounds__(256) void swizzle2_kernel(const float* __restrict__ msg_w1,
                                                       short* __restrict__ dst, int total){
    int gid = blockIdx.x*256 + threadIdx.x;
    if (gid >= total) return;
    int layer = gid / 18432;
    int e     = gid % 18432;
    int ksg = e / 6144;
    int rem = e % 6144;
    int nt   = rem >> 9;
    int r2   = rem & 511;
    int lane = r2 >> 3;
    int jx   = r2 & 7;
    int k = ksg*32 + ((lane >> 4) << 3) + jx;     // 0..95
    int f = nt*16 + (lane & 15);                  // 0..191
    int row = (f < 96) ? k : (96 + k);
    int col = (f < 96) ? f : (f - 96);
    dst[gid] = f2bf(msg_w1[(size_t)layer*193*96 + (size_t)row*96 + col]);
}

// ---------------- edge sorting (counting sort by rec) ----------------
__global__ __launch_bounds__(256) void hist_kernel(const int* __restrict__ rec, int* __restrict__ deg, int E){
    int e = blockIdx.x*256 + threadIdx.x;
    if (e < E) atomicAdd(&deg[rec[e]], 1);
}

__global__ __launch_bounds__(256) void scan_part(const int* __restrict__ deg, int* __restrict__ part, int N){
    __shared__ int red[256];
    const int t = threadIdx.x;
    int base = blockIdx.x*1024;
    int s = 0;
    #pragma unroll
    for (int j=0;j<4;j++){ int i = base + j*256 + t; s += (i<N)?deg[i]:0; }
    red[t]=s; __syncthreads();
    #pragma unroll
    for (int off=128; off>0; off>>=1){ if (t<off) red[t]+=red[t+off]; __syncthreads(); }
    if (t==0) part[blockIdx.x]=red[0];
}
__global__ __launch_bounds__(256) void scan_top(int* __restrict__ part, int nb){
    __shared__ int buf[256];
    const int t = threadIdx.x;
    int v = (t < nb) ? part[t] : 0;
    buf[t] = v;
    __syncthreads();
    #pragma unroll
    for (int off=1; off<256; off<<=1){
        int u = (t>=off)?buf[t-off]:0;
        __syncthreads();
        buf[t] += u;
        __syncthreads();
    }
    if (t < nb) part[t] = buf[t] - v;
}
__global__ __launch_bounds__(256) void scan_final(const int* __restrict__ deg, const int* __restrict__ part,
                                                  int* __restrict__ cur, int N){
    __shared__ int tsum[256];
    const int t = threadIdx.x;
    int i0 = blockIdx.x*1024 + t*4;
    int a0 = (i0+0<N)?deg[i0+0]:0;
    int a1 = (i0+1<N)?deg[i0+1]:0;
    int a2 = (i0+2<N)?deg[i0+2]:0;
    int a3 = (i0+3<N)?deg[i0+3]:0;
    int s = a0+a1+a2+a3;
    tsum[t]=s; __syncthreads();
    #pragma unroll
    for (int off=1; off<256; off<<=1){
        int u = (t>=off)?tsum[t-off]:0;
        __syncthreads();
        tsum[t]+=u;
        __syncthreads();
    }
    int excl = tsum[t]-s + part[blockIdx.x];
    if (i0+0<N) cur[i0+0]=excl;
    if (i0+1<N) cur[i0+1]=excl+a0;
    if (i0+2<N) cur[i0+2]=excl+a0+a1;
    if (i0+3<N) cur[i0+3]=excl+a0+a1+a2;
}

__global__ __launch_bounds__(256) void scatter_kernel(
    const int* __restrict__ send, const int* __restrict__ rec, const float* __restrict__ pos,
    int* __restrict__ cur, int* __restrict__ send_s, int* __restrict__ rec_s,
    float* __restrict__ dist_s, int E)
{
    int e = blockIdx.x*256 + threadIdx.x;
    if (e >= E) return;
    int s = send[e], r = rec[e];
    int p = atomicAdd(&cur[r], 1);
    send_s[p] = s;
    rec_s[p]  = r;
    float dx = pos[3*s]   - pos[3*r];
    float dy = pos[3*s+1] - pos[3*r+1];
    float dz = pos[3*s+2] - pos[3*r+2];
    dist_s[p] = sqrtf(dx*dx + dy*dy + dz*dz);
}

// ---------------- edge: gather SR, silu into B-frags, GEMM2, segment-reduce ----------------
__global__ __launch_bounds__(256,5) void edge_kernel(
    const short* __restrict__ SR,
    const int* __restrict__ send_s, const int* __restrict__ rec_s, const float* __restrict__ dist_s,
    const float* __restrict__ w1r192,
    const short* __restrict__ w2sw, const float* __restrict__ b2,
    float* __restrict__ aggr, int E)
{
    __shared__ short msgS[TILE*104];     // bf16 messages, 26624 B
    __shared__ int   recS[TILE];
    __shared__ int   startIdxS[TILE+1];
    __shared__ int   wcntS[2];
    const int t  = threadIdx.x;
    const int e0 = blockIdx.x * TILE;

    if (t < TILE) {
        int e = e0 + t; if (e >= E) e = E - 1;
        recS[t] = rec_s[e];
    }
    __syncthreads();

    // segment table via ballot
    bool flag = false;
    if (t < TILE) flag = (t == 0) || (recS[t] != recS[t-1]);
    unsigned long long bmask = __ballot(flag ? 1 : 0);
    int pre = __popcll(bmask & ((1ull << (t & 63)) - 1ull));
    if (t < TILE && (t & 63) == 0) wcntS[t >> 6] = __popcll(bmask);
    __syncthreads();
    const int nseg = wcntS[0] + wcntS[1];
    if (flag) startIdxS[pre + ((t >> 6) ? wcntS[0] : 0)] = t;
    if (t == 0) startIdxS[nseg] = TILE;
    // visible after the pre-segsum barrier

    const int lane = t & 63;
    const int wv   = t >> 6;
    const int e_lo = wv * 32;
    const int col  = lane & 15;
    const int quad = lane >> 4;
    const int frow = quad * 4;
    const float4v fzero = {0.f,0.f,0.f,0.f};

    // build this lane's own B-fragments: t1[e][f], f = ks*32 + quad*8 + j
    short8 frag[2][3];
    #pragma unroll
    for (int et=0; et<2; ++et){
        int ei = e_lo + et*16 + col;
        int ec = e0 + ei; if (ec >= E) ec = E - 1;
        int se = send_s[ec];
        int re = recS[ei];
        float d = dist_s[ec];
        #pragma unroll
        for (int ks=0; ks<3; ++ks){
            int f0 = ks*32 + quad*8;
            short8 S8 = *(const short8*)(SR + (size_t)se*192 + f0);
            short8 R8 = *(const short8*)(SR + (size_t)re*192 + 96 + f0);
            float4v wa = *(const float4v*)(w1r192 + f0);
            float4v wb = *(const float4v*)(w1r192 + f0 + 4);
            short8 fr;
            #pragma unroll
            for (int j=0;j<8;j++){
                float w = (j<4) ? wa[j] : wb[j-4];
                float v = bf2f(S8[j]) + bf2f(R8[j]) + d*w;
                fr[j] = f2bf(silu_f(v));
            }
            frag[et][ks] = fr;
        }
    }

    float4v acc2[2][6];
    #pragma unroll
    for (int i=0;i<2;i++)
      #pragma unroll
      for (int n=0;n<6;n++) acc2[i][n] = fzero;

    const short8* w2f = (const short8*)w2sw;
    #pragma unroll
    for (int ks = 0; ks < 3; ++ks) {
        #pragma unroll
        for (int mt = 0; mt < 6; ++mt) {
            short8 a = w2f[(ks*6+mt)*64 + lane];
            acc2[0][mt] = __builtin_amdgcn_mfma_f32_16x16x32_bf16(a, frag[0][ks], acc2[0][mt], 0, 0, 0);
            acc2[1][mt] = __builtin_amdgcn_mfma_f32_16x16x32_bf16(a, frag[1][ks], acc2[1][mt], 0, 0, 0);
        }
    }
    float4v b2v[6];
    #pragma unroll
    for (int mt=0; mt<6; ++mt) b2v[mt] = *(const float4v*)(b2 + mt*16 + frow);

    #pragma unroll
    for (int et=0; et<2; ++et){
        int e = e_lo + et*16 + col;
        bool valid = (e0 + e) < E;
        #pragma unroll
        for (int mt=0; mt<6; ++mt){
            short4v sv;
            #pragma unroll
            for (int r=0;r<4;r++){
                float u = silu_f(acc2[et][mt][r] + b2v[mt][r]);
                sv[r] = f2bf(valid ? u : 0.0f);
            }
            *(short4v*)(msgS + e*104 + mt*16 + frow) = sv;
        }
    }
    __syncthreads();

    // segment-sum: item = (segment, 8-col group), short8 reads, fp32 accumulate
    const int items = nseg * 12;
    for (int item = t; item < items; item += 256){
        int s  = item / 12;
        int fg = item - s*12;
        int r0 = startIdxS[s], r1 = startIdxS[s+1];
        float sum[8] = {0.f,0.f,0.f,0.f,0.f,0.f,0.f,0.f};
        for (int r = r0; r < r1; ++r){
            short8 v8 = *(const short8*)(msgS + r*104 + fg*8);
            #pragma unroll
            for (int j=0;j<8;j++) sum[j] += bf2f(v8[j]);
        }
        float* dstp = aggr + (size_t)recS[r0]*HDIM + fg*8;
        #pragma unroll
        for (int j=0;j<8;j++) atomicAdd(dstp+j, sum[j]);
    }
}

// ---------------- node update: h += MLP([h, aggr]); re-zero aggr; optional SR for next layer ----------------
__global__ __launch_bounds__(256,3) void update_kernel(
    float* __restrict__ h, short* __restrict__ hbf, float* __restrict__ aggr,
    const short* __restrict__ w1sw, const float* __restrict__ b1,
    const short* __restrict__ w2sw, const float* __restrict__ b2,
    const short* __restrict__ w1sr_next, const float* __restrict__ msgb1_next,
    short* __restrict__ SR, int N)
{
    __shared__ short stateS[TILE*200];
    const int t  = threadIdx.x;
    const int n0 = blockIdx.x * TILE;

    #pragma unroll
    for (int it = 0; it < 12; ++it) {
        int q = it*256 + t;    // 128 rows * 24 chunks
        int c = q % 24;
        int i = q / 24;
        int node = n0 + i;
        if (c < 12) {
            uint4v v = {0u,0u,0u,0u};
            if (node < N) v = *(const uint4v*)(hbf + (size_t)node*HDIM + c*8);
            *(uint4v*)(stateS + i*200 + c*8) = v;
        } else {
            int cc = c - 12;
            short8 s8 = {0,0,0,0,0,0,0,0};
            if (node < N) {
                float4v a0 = *(const float4v*)(aggr + (size_t)node*HDIM + cc*8);
                float4v a1 = *(const float4v*)(aggr + (size_t)node*HDIM + cc*8 + 4);
                s8[0]=f2bf(a0[0]); s8[1]=f2bf(a0[1]); s8[2]=f2bf(a0[2]); s8[3]=f2bf(a0[3]);
                s8[4]=f2bf(a1[0]); s8[5]=f2bf(a1[1]); s8[6]=f2bf(a1[2]); s8[7]=f2bf(a1[3]);
            }
            *(short8*)(stateS + i*200 + HDIM + cc*8) = s8;
        }
    }
    __syncthreads();

    const int lane = t & 63;
    const int wv   = t >> 6;
    const int e_lo = wv * 32;
    const int col  = lane & 15;
    const int quad = lane >> 4;
    const int koff = quad * 8;
    const int frow = quad * 4;
    const float4v fzero = {0.f,0.f,0.f,0.f};

    float4v acc[2][6];
    #pragma unroll
    for (int i=0;i<2;i++)
      #pragma unroll
      for (int n=0;n<6;n++) acc[i][n] = fzero;

    const short8* w1f = (const short8*)w1sw;
    #pragma unroll
    for (int ks = 0; ks < 6; ++ks) {
        short8 bb0 = *(const short8*)(stateS + (e_lo+col)*200    + ks*32 + koff);
        short8 bb1 = *(const short8*)(stateS + (e_lo+16+col)*200 + ks*32 + koff);
        #pragma unroll
        for (int mt = 0; mt < 6; ++mt) {
            short8 a = w1f[(ks*6+mt)*64 + lane];
            acc[0][mt] = __builtin_amdgcn_mfma_f32_16x16x32_bf16(a, bb0, acc[0][mt], 0, 0, 0);
            acc[1][mt] = __builtin_amdgcn_mfma_f32_16x16x32_bf16(a, bb1, acc[1][mt], 0, 0, 0);
        }
    }
    float4v b1v[6];
    #pragma unroll
    for (int mt=0; mt<6; ++mt) b1v[mt] = *(const float4v*)(b1 + mt*16 + frow);
    __syncthreads();

    short* t1S = stateS;   // stride 104
    #pragma unroll
    for (int et=0; et<2; ++et){
        int e = e_lo + et*16 + col;
        #pragma unroll
        for (int mt=0; mt<6; ++mt){
            short4v sv;
            #pragma unroll
            for (int r=0;r<4;r++) sv[r] = f2bf(silu_f(acc[et][mt][r] + b1v[mt][r]));
            *(short4v*)(t1S + e*104 + mt*16 + frow) = sv;
        }
    }
    __syncthreads();

    float4v acc2[2][6];
    #pragma unroll
    for (int i=0;i<2;i++)
      #pragma unroll
      for (int n=0;n<6;n++) acc2[i][n] = fzero;

    const short8* w2f = (const short8*)w2sw;
    #pragma unroll
    for (int ks = 0; ks < 3; ++ks) {
        short8 bb0 = *(const short8*)(t1S + (e_lo+col)*104    + ks*32 + koff);
        short8 bb1 = *(const short8*)(t1S + (e_lo+16+col)*104 + ks*32 + koff);
        #pragma unroll
        for (int mt = 0; mt < 6; ++mt) {
            short8 a = w2f[(ks*6+mt)*64 + lane];
            acc2[0][mt] = __builtin_amdgcn_mfma_f32_16x16x32_bf16(a, bb0, acc2[0][mt], 0, 0, 0);
            acc2[1][mt] = __builtin_amdgcn_mfma_f32_16x16x32_bf16(a, bb1, acc2[1][mt], 0, 0, 0);
        }
    }
    float4v b2v[6];
    #pragma unroll
    for (int mt=0; mt<6; ++mt) b2v[mt] = *(const float4v*)(b2 + mt*16 + frow);
    __syncthreads();   // all GEMM2 t1 reads done; we will overwrite with new-h bf16

    #pragma unroll
    for (int et=0; et<2; ++et){
        int erow = e_lo + et*16 + col;
        int node = n0 + erow;
        bool valid = node < N;
        size_t base = (size_t)node*HDIM;
        #pragma unroll
        for (int mt=0; mt<6; ++mt){
            int f0 = mt*16 + frow;
            float4v old = valid ? *(const float4v*)(h + base + f0) : fzero;
            float4v o;
            #pragma unroll
            for (int r=0;r<4;r++) o[r] = old[r] + acc2[et][mt][r] + b2v[mt][r];
            short4v sv = {f2bf(o[0]), f2bf(o[1]), f2bf(o[2]), f2bf(o[3])};
            if (valid) {
                *(float4v*)(h + base + f0) = o;
                *(short4v*)(hbf + base + f0) = sv;
                *(float4v*)(aggr + base + f0) = fzero;
            }
            *(short4v*)(stateS + erow*104 + f0) = sv;   // new h, bf16, stride 104
        }
    }

    if (w1sr_next) {   // produce SR for the next layer's edge kernel
        __syncthreads();
        float4v accS[2][12];
        #pragma unroll
        for (int i=0;i<2;i++)
          #pragma unroll
          for (int n=0;n<12;n++) accS[i][n] = fzero;

        const short8* wsf = (const short8*)w1sr_next;
        #pragma unroll
        for (int ks = 0; ks < 3; ++ks) {
            short8 bb0 = *(const short8*)(stateS + (e_lo+col)*104    + ks*32 + koff);
            short8 bb1 = *(const short8*)(stateS + (e_lo+16+col)*104 + ks*32 + koff);
            #pragma unroll
            for (int mt = 0; mt < 12; ++mt) {
                short8 a = wsf[(ks*12+mt)*64 + lane];
                accS[0][mt] = __builtin_amdgcn_mfma_f32_16x16x32_bf16(a, bb0, accS[0][mt], 0, 0, 0);
                accS[1][mt] = __builtin_amdgcn_mfma_f32_16x16x32_bf16(a, bb1, accS[1][mt], 0, 0, 0);
            }
        }
        float4v bnv[6];
        #pragma unroll
        for (int mt=0; mt<6; ++mt) bnv[mt] = *(const float4v*)(msgb1_next + mt*16 + frow);

        #pragma unroll
        for (int et=0; et<2; ++et){
            int node = n0 + e_lo + et*16 + col;
            if (node < N) {
                size_t sbase = (size_t)node*192;
                #pragma unroll
                for (int mt=0; mt<12; ++mt){
                    float4v o = accS[et][mt];
                    if (mt < 6) { o[0]+=bnv[mt][0]; o[1]+=bnv[mt][1]; o[2]+=bnv[mt][2]; o[3]+=bnv[mt][3]; }
                    short4v sv = {f2bf(o[0]), f2bf(o[1]), f2bf(o[2]), f2bf(o[3])};
                    *(short4v*)(SR + sbase + mt*16 + frow) = sv;
                }
            }
        }
    }
}

// ---------------- embed: h = silu([x|pe] W1 + b1) W2 + b2 ; + SR for layer 0 ----------------
__global__ __launch_bounds__(256,3) void embed_kernel(
    const float* __restrict__ x, const float* __restrict__ pe,
    const short* __restrict__ w1sw, const float* __restrict__ b1,
    const short* __restrict__ w2sw, const float* __restrict__ b2,
    float* __restrict__ h, short* __restrict__ hbf,
    const short* __restrict__ w1sr0, const float* __restrict__ msgb1_0,
    short* __restrict__ SR, int N)
{
    __shared__ short stateS[TILE*72];
    __shared__ short t1S[TILE*104];
    const int t  = threadIdx.x;
    const int n0 = blockIdx.x * TILE;

    if (t < TILE) {
        int node = n0 + t;
        short* row = stateS + t*72;
        if (node < N) {
            #pragma unroll
            for (int j=0;j<11;j++) row[j]    = f2bf(x[(size_t)node*11 + j]);
            #pragma unroll
            for (int j=0;j<24;j++) row[11+j] = f2bf(pe[(size_t)node*24 + j]);
            #pragma unroll
            for (int j=35;j<64;j++) row[j] = 0;
        } else {
            #pragma unroll
            for (int j=0;j<64;j++) row[j] = 0;
        }
    }
    __syncthreads();

    const int lane = t & 63;
    const int wv   = t >> 6;
    const int e_lo = wv * 32;
    const int col  = lane & 15;
    const int quad = lane >> 4;
    const int koff = quad * 8;
    const int frow = quad * 4;
    const float4v fzero = {0.f,0.f,0.f,0.f};

    float4v acc[2][6];
    #pragma unroll
    for (int i=0;i<2;i++)
      #pragma unroll
      for (int n=0;n<6;n++) acc[i][n] = fzero;

    const short8* w1f = (const short8*)w1sw;
    #pragma unroll
    for (int ks = 0; ks < 2; ++ks) {
        short8 bb0 = *(const short8*)(stateS + (e_lo+col)*72    + ks*32 + koff);
        short8 bb1 = *(const short8*)(stateS + (e_lo+16+col)*72 + ks*32 + koff);
        #pragma unroll
        for (int mt = 0; mt < 6; ++mt) {
            short8 a = w1f[(ks*6+mt)*64 + lane];
            acc[0][mt] = __builtin_amdgcn_mfma_f32_16x16x32_bf16(a, bb0, acc[0][mt], 0, 0, 0);
            acc[1][mt] = __builtin_amdgcn_mfma_f32_16x16x32_bf16(a, bb1, acc[1][mt], 0, 0, 0);
        }
    }
    float4v b1v[6];
    #pragma unroll
    for (int mt=0; mt<6; ++mt) b1v[mt] = *(const float4v*)(b1 + mt*16 + frow);

    #pragma unroll
    for (int et=0; et<2; ++et){
        int e = e_lo + et*16 + col;
        #pragma unroll
        for (int mt=0; mt<6; ++mt){
            short4v sv;
            #pragma unroll
            for (int r=0;r<4;r++) sv[r] = f2bf(silu_f(acc[et][mt][r] + b1v[mt][r]));
            *(short4v*)(t1S + e*104 + mt*16 + frow) = sv;
        }
    }
    __syncthreads();

    float4v acc2[2][6];
    #pragma unroll
    for (int i=0;i<2;i++)
      #pragma unroll
      for (int n=0;n<6;n++) acc2[i][n] = fzero;

    const short8* w2f = (const short8*)w2sw;
    #pragma unroll
    for (int ks = 0; ks < 3; ++ks) {
        short8 bb0 = *(const short8*)(t1S + (e_lo+col)*104    + ks*32 + koff);
        short8 bb1 = *(const short8*)(t1S + (e_lo+16+col)*104 + ks*32 + koff);
        #pragma unroll
        for (int mt = 0; mt < 6; ++mt) {
            short8 a = w2f[(ks*6+mt)*64 + lane];
            acc2[0][mt] = __builtin_amdgcn_mfma_f32_16x16x32_bf16(a, bb0, acc2[0][mt], 0, 0, 0);
            acc2[1][mt] = __builtin_amdgcn_mfma_f32_16x16x32_bf16(a, bb1, acc2[1][mt], 0, 0, 0);
        }
    }
    float4v b2v[6];
    #pragma unroll
    for (int mt=0; mt<6; ++mt) b2v[mt] = *(const float4v*)(b2 + mt*16 + frow);
    __syncthreads();   // GEMM2 t1 reads done; reuse t1S for new-h bf16

    #pragma unroll
    for (int et=0; et<2; ++et){
        int erow = e_lo + et*16 + col;
        int node = n0 + erow;
        bool valid = node < N;
        size_t base = (size_t)node*HDIM;
        #pragma unroll
        for (int mt=0; mt<6; ++mt){
            int f0 = mt*16 + frow;
            float4v o;
            #pragma unroll
            for (int r=0;r<4;r++) o[r] = acc2[et][mt][r] + b2v[mt][r];
            short4v sv = {f2bf(o[0]), f2bf(o[1]), f2bf(o[2]), f2bf(o[3])};
            if (valid) {
                *(float4v*)(h + base + f0) = o;
                *(short4v*)(hbf + base + f0) = sv;
            }
            *(short4v*)(t1S + erow*104 + f0) = sv;
        }
    }
    __syncthreads();

    // SR for layer 0
    float4v accS[2][12];
    #pragma unroll
    for (int i=0;i<2;i++)
      #pragma unroll
      for (int n=0;n<12;n++) accS[i][n] = fzero;

    const short8* wsf = (const short8*)w1sr0;
    #pragma unroll
    for (int ks = 0; ks < 3; ++ks) {
        short8 bb0 = *(const short8*)(t1S + (e_lo+col)*104    + ks*32 + koff);
        short8 bb1 = *(const short8*)(t1S + (e_lo+16+col)*104 + ks*32 + koff);
        #pragma unroll
        for (int mt = 0; mt < 12; ++mt) {
            short8 a = wsf[(ks*12+mt)*64 + lane];
            accS[0][mt] = __builtin_amdgcn_mfma_f32_16x16x32_bf16(a, bb0, accS[0][mt], 0, 0, 0);
            accS[1][mt] = __builtin_amdgcn_mfma_f32_16x16x32_bf16(a, bb1, accS[1][mt], 0, 0, 0);
        }
    }
    float4v bnv[6];
    #pragma unroll
    for (int mt=0; mt<6; ++mt) bnv[mt] = *(const float4v*)(msgb1_0 + mt*16 + frow);

    #pragma unroll
    for (int et=0; et<2; ++et){
        int node = n0 + e_lo + et*16 + col;
        if (node < N) {
            size_t sbase = (size_t)node*192;
            #pragma unroll
            for (int mt=0; mt<12; ++mt){
                float4v o = accS[et][mt];
                if (mt < 6) { o[0]+=bnv[mt][0]; o[1]+=bnv[mt][1]; o[2]+=bnv[mt][2]; o[3]+=bnv[mt][3]; }
                short4v sv = {f2bf(o[0]), f2bf(o[1]), f2bf(o[2]), f2bf(o[3])};
                *(short4v*)(SR + sbase + mt*16 + frow) = sv;
            }
        }
    }
}

// ---------------- pre-MLP + pooling, segment-reduced over sorted batch ----------------
__global__ __launch_bounds__(256,2) void prepool_kernel(
    const short* __restrict__ hbf,
    const short* __restrict__ w1sw, const float* __restrict__ b1,
    const short* __restrict__ w2sw, const float* __restrict__ b2,
    const int* __restrict__ batch, float* __restrict__ pooled, int N)
{
    __shared__ short bufS[TILE*104*2];   // 53248 B: state | t1 ; later msg fp32 (51200 B)
    __shared__ int   batchS[TILE];
    __shared__ int   startIdxS[TILE+1];
    __shared__ int   wcntS[2];
    short* stateS = bufS;                 // stride 104
    short* t1S    = bufS + TILE*104;      // stride 104
    float* msgS   = (float*)bufS;         // stride 100
    const int t  = threadIdx.x;
    const int n0 = blockIdx.x * TILE;

    #pragma unroll
    for (int it = 0; it < 6; ++it) {
        int q = it*256 + t;
        int c = q % 12;
        int i = q / 12;
        int node = n0 + i;
        uint4v v = {0u,0u,0u,0u};
        if (node < N) v = *(const uint4v*)(hbf + (size_t)node*HDIM + c*8);
        *(uint4v*)(stateS + i*104 + c*8) = v;
    }
    if (t < TILE) {
        int node = n0 + t;
        batchS[t] = batch[node < N ? node : N-1];
    }
    __syncthreads();

    bool flag = false;
    if (t < TILE) flag = (t == 0) || (batchS[t] != batchS[t-1]);
    unsigned long long bmask = __ballot(flag ? 1 : 0);
    int pre = __popcll(bmask & ((1ull << (t & 63)) - 1ull));
    if (t < TILE && (t & 63) == 0) wcntS[t >> 6] = __popcll(bmask);

    const int lane = t & 63;
    const int wv   = t >> 6;
    const int e_lo = wv * 32;
    const int col  = lane & 15;
    const int quad = lane >> 4;
    const int koff = quad * 8;
    const int frow = quad * 4;
    const float4v fzero = {0.f,0.f,0.f,0.f};

    float4v acc[2][6];
    #pragma unroll
    for (int i=0;i<2;i++)
      #pragma unroll
      for (int n=0;n<6;n++) acc[i][n] = fzero;

    const short8* w1f = (const short8*)w1sw;
    #pragma unroll
    for (int ks = 0; ks < 3; ++ks) {
        short8 bb0 = *(const short8*)(stateS + (e_lo+col)*104    + ks*32 + koff);
        short8 bb1 = *(const short8*)(stateS + (e_lo+16+col)*104 + ks*32 + koff);
        #pragma unroll
        for (int mt = 0; mt < 6; ++mt) {
            short8 a = w1f[(ks*6+mt)*64 + lane];
            acc[0][mt] = __builtin_amdgcn_mfma_f32_16x16x32_bf16(a, bb0, acc[0][mt], 0, 0, 0);
            acc[1][mt] = __builtin_amdgcn_mfma_f32_16x16x32_bf16(a, bb1, acc[1][mt], 0, 0, 0);
        }
    }
    float4v b1v[6];
    #pragma unroll
    for (int mt=0; mt<6; ++mt) b1v[mt] = *(const float4v*)(b1 + mt*16 + frow);

    #pragma unroll
    for (int et=0; et<2; ++et){
        int e = e_lo + et*16 + col;
        #pragma unroll
        for (int mt=0; mt<6; ++mt){
            short4v sv;
            #pragma unroll
            for (int r=0;r<4;r++) sv[r] = f2bf(silu_f(acc[et][mt][r] + b1v[mt][r]));
            *(short4v*)(t1S + e*104 + mt*16 + frow) = sv;
        }
    }
    __syncthreads();
    const int nseg = wcntS[0] + wcntS[1];
    if (flag) startIdxS[pre + ((t >> 6) ? wcntS[0] : 0)] = t;
    if (t == 0) startIdxS[nseg] = TILE;

    float4v acc2[2][6];
    #pragma unroll
    for (int i=0;i<2;i++)
      #pragma unroll
      for (int n=0;n<6;n++) acc2[i][n] = fzero;

    const short8* w2f = (const short8*)w2sw;
    #pragma unroll
    for (int ks = 0; ks < 3; ++ks) {
        short8 bb0 = *(const short8*)(t1S + (e_lo+col)*104    + ks*32 + koff);
        short8 bb1 = *(const short8*)(t1S + (e_lo+16+col)*104 + ks*32 + koff);
        #pragma unroll
        for (int mt = 0; mt < 6; ++mt) {
            short8 a = w2f[(ks*6+mt)*64 + lane];
            acc2[0][mt] = __builtin_amdgcn_mfma_f32_16x16x32_bf16(a, bb0, acc2[0][mt], 0, 0, 0);
            acc2[1][mt] = __builtin_amdgcn_mfma_f32_16x16x32_bf16(a, bb1, acc2[1][mt], 0, 0, 0);
        }
    }
    float4v b2v[6];
    #pragma unroll
    for (int mt=0; mt<6; ++mt) b2v[mt] = *(const float4v*)(b2 + mt*16 + frow);
    __syncthreads();   // t1 reads done; msg overwrites buf

    #pragma unroll
    for (int et=0; et<2; ++et){
        int e = e_lo + et*16 + col;
        bool valid = (n0 + e) < N;
        #pragma unroll
        for (int mt=0; mt<6; ++mt){
            float4v v;
            #pragma unroll
            for (int r=0;r<4;r++){
                float u = acc2[et][mt][r] + b2v[mt][r];
                v[r] = valid ? u : 0.0f;
            }
            *(float4v*)(msgS + e*100 + mt*16 + frow) = v;
        }
    }
    __syncthreads();

    const int items = nseg * 24;
    for (int item = t; item < items; item += 256){
        int s  = item / 24;
        int fg = item - s*24;
        int r0 = startIdxS[s], r1 = startIdxS[s+1];
        float4v sum = fzero;
        for (int r = r0; r < r1; ++r) sum += *(const float4v*)(msgS + r*100 + fg*4);
        float* dstp = pooled + (size_t)batchS[r0]*HDIM + fg*4;
        atomicAdd(dstp+0, sum[0]);
        atomicAdd(dstp+1, sum[1]);
        atomicAdd(dstp+2, sum[2]);
        atomicAdd(dstp+3, sum[3]);
    }
}

// ---------------- readout ----------------
__global__ __launch_bounds__(128) void readout_kernel(
    const float* __restrict__ pooled,
    const float* __restrict__ w1, const float* __restrict__ b1,
    const float* __restrict__ w2, const float* __restrict__ b2,
    float* __restrict__ out)
{
    __shared__ float red[128];
    const int g = blockIdx.x;
    const int t = threadIdx.x;
    float p = 0.0f;
    if (t < HDIM) {
        float acc = b1[t];
        for (int k = 0; k < HDIM; ++k)
            acc += pooled[(size_t)g*HDIM + k] * w1[(size_t)k*HDIM + t];
        acc = silu_f(acc);
        p = acc * w2[t];
    }
    red[t] = p;
    __syncthreads();
    for (int s = 64; s > 0; s >>= 1) {
        if (t < s) red[t] += red[t + s];
        __syncthreads();
    }
    if (t == 0) out[g] = red[0] + b2[0];
}

extern "C" void kernel_launch(void* const* d_in, const int* in_sizes, int n_in,
                              void* d_out, int out_size, void* d_ws, size_t ws_size,
                              hipStream_t stream)
{
    const float* x        = (const float*)d_in[0];
    const float* pos      = (const float*)d_in[1];
    const float* pe       = (const float*)d_in[2];
    const int*   ei       = (const int*)d_in[3];
    const int*   batch    = (const int*)d_in[4];
    const float* embed_w1 = (const float*)d_in[5];
    const float* embed_b1 = (const float*)d_in[6];
    const float* embed_w2 = (const float*)d_in[7];
    const float* embed_b2 = (const float*)d_in[8];
    const float* msg_w1   = (const float*)d_in[9];
    const float* msg_b1   = (const float*)d_in[10];
    const float* msg_w2   = (const float*)d_in[11];
    const float* msg_b2   = (const float*)d_in[12];
    const float* upd_w1   = (const float*)d_in[13];
    const float* upd_b1   = (const float*)d_in[14];
    const float* upd_w2   = (const float*)d_in[15];
    const float* upd_b2   = (const float*)d_in[16];
    const float* pre_w1   = (const float*)d_in[17];
    const float* pre_b1   = (const float*)d_in[18];
    const float* pre_w2   = (const float*)d_in[19];
    const float* pre_b2   = (const float*)d_in[20];
    const float* ro_w1    = (const float*)d_in[21];
    const float* ro_b1    = (const float*)d_in[22];
    const float* ro_w2    = (const float*)d_in[23];
    const float* ro_b2    = (const float*)d_in[24];

    const int E = in_sizes[3] / 2;
    const int N = in_sizes[4];
    const int G = out_size;

    char* ws = (char*)d_ws;
    size_t off = 0;
    auto alloc = [&](size_t bytes){ void* p = ws + off; off += (bytes + 255) & ~(size_t)255; return p; };
    float* h      = (float*)alloc((size_t)N*HDIM*4);
    short* hbf    = (short*)alloc((size_t)N*HDIM*2);
    float* aggr   = (float*)alloc((size_t)N*HDIM*4);
    float* pooled = (float*)alloc((size_t)G*HDIM*4);
    short* wsw    = (short*)alloc((size_t)59*3072*2);
    short* w1sr   = (short*)alloc((size_t)4*18432*2);
    short* SR     = (short*)alloc((size_t)N*192*2);
    int*   deg    = (int*)alloc((size_t)N*4);
    int*   cur    = (int*)alloc((size_t)N*4);
    int*   part   = (int*)alloc((size_t)256*4);
    int*   send_s = (int*)alloc((size_t)E*4);
    int*   rec_s  = (int*)alloc((size_t)E*4);
    float* dist_s = (float*)alloc((size_t)E*4);

    hipMemsetAsync(aggr,   0, (size_t)N*HDIM*4, stream);
    hipMemsetAsync(pooled, 0, (size_t)G*HDIM*4, stream);
    hipMemsetAsync(deg,    0, (size_t)N*4, stream);

    SwTable T;
    for (int jj=0;jj<22;jj++){ T.j[jj].src = embed_w1; T.j[jj].ck = 1<<30; T.j[jj].ks = 0; T.j[jj].ksrc = 0; }
    int ck = 0, ji = 0;
    auto add = [&](const float* s, int ks, int ksrc){
        T.j[ji].src = s; T.j[ji].ck = ck; T.j[ji].ks = ks; T.j[ji].ksrc = ksrc;
        ji++; ck += ks;
    };
    add(embed_w1, 2, 35);   // ck 0
    add(embed_w2, 3, 96);   // ck 2
    add(pre_w1,   3, 96);   // ck 5
    add(pre_w2,   3, 96);   // ck 8
    for (int l=0;l<4;l++) add(msg_w2 + (size_t)l*96*96,  3, 96);   // ck 11+3l
    for (int l=0;l<4;l++) add(upd_w1 + (size_t)l*192*96, 6, 192);  // ck 23+6l
    for (int l=0;l<4;l++) add(upd_w2 + (size_t)l*96*96,  3, 96);   // ck 47+3l
    const int total = 59*3072;
    swizzle_kernel<<<(total+255)/256, 256, 0, stream>>>(T, wsw, total);
    const int total2 = 4*18432;
    swizzle2_kernel<<<(total2+255)/256, 256, 0, stream>>>(msg_w1, w1sr, total2);

    const int nbE256 = (E + 255) / 256;
    const int nbScan = (N + 1023) / 1024;
    hist_kernel<<<nbE256, 256, 0, stream>>>(ei + E, deg, E);
    scan_part<<<nbScan, 256, 0, stream>>>(deg, part, N);
    scan_top<<<1, 256, 0, stream>>>(part, nbScan);
    scan_final<<<nbScan, 256, 0, stream>>>(deg, part, cur, N);
    scatter_kernel<<<nbE256, 256, 0, stream>>>(ei, ei + E, pos, cur, send_s, rec_s, dist_s, E);

    const int nbN = (N + TILE - 1) / TILE;
    embed_kernel<<<nbN, 256, 0, stream>>>(x, pe, wsw + 0, embed_b1, wsw + 2*3072, embed_b2,
                                          h, hbf, w1sr, msg_b1, SR, N);

    const int nbE = (E + TILE - 1) / TILE;
    for (int l = 0; l < 4; ++l) {
        edge_kernel<<<nbE, 256, 0, stream>>>(SR, send_s, rec_s, dist_s,
            msg_w1 + (size_t)l*193*96 + (size_t)192*96,
            wsw + (11 + 3*l)*3072, msg_b2 + l*96, aggr, E);
        const short* w1sr_next = (l < 3) ? (w1sr + (size_t)(l+1)*18432) : nullptr;
        const float* msgb1_next = (l < 3) ? (msg_b1 + (l+1)*96) : nullptr;
        update_kernel<<<nbN, 256, 0, stream>>>(h, hbf, aggr,
            wsw + (23 + 6*l)*3072, upd_b1 + l*96,
            wsw + (47 + 3*l)*3072, upd_b2 + l*96,
            w1sr_next, msgb1_next, SR, N);
    }

    prepool_kernel<<<nbN, 256, 0, stream>>>(hbf, wsw + 5*3072, pre_b1, wsw + 8*3072, pre_b2,
                                            batch, pooled, N);
    readout_kernel<<<G, 128, 0, stream>>>(pooled, ro_w1, ro_b1, ro_w2, ro_b2, (float*)d_out);
}

// Round 6
// 766.113 us; speedup vs baseline: 1.4418x; 1.4418x over previous
//
#include <hip/hip_runtime.h>
#include <hip/hip_bf16.h>

#define HDIM 96
#define TILE 128

typedef __attribute__((ext_vector_type(8))) short  short8;
typedef __attribute__((ext_vector_type(4))) short  short4v;
typedef __attribute__((ext_vector_type(4))) float  float4v;
typedef __attribute__((ext_vector_type(4))) unsigned int uint4v;

static __device__ __forceinline__ short f2bf(float f){
    __hip_bfloat16 h = __float2bfloat16(f);
    return *reinterpret_cast<short*>(&h);
}
static __device__ __forceinline__ float bf2f(short s){
    unsigned u = ((unsigned)(unsigned short)s) << 16;
    return __uint_as_float(u);
}
// fast silu: v * rcp(1+exp(-v)) — v_rcp_f32 is ~1ulp, fine at bf16 tolerance
static __device__ __forceinline__ float silu_f(float v){
    return v * __builtin_amdgcn_rcpf(1.0f + __expf(-v));
}

// ---------------- weight swizzle into MFMA A-fragment order ----------------
// frag[lane][j] = W[k0 + (lane>>4)*8 + j][nt*16 + (lane&15)]
struct SwJob { const float* src; int ck; int ks; int ksrc; };
struct SwTable { SwJob j[22]; };

__global__ __launch_bounds__(256) void swizzle_kernel(SwTable T, short* __restrict__ dst, int total){
    int gid = blockIdx.x*256 + threadIdx.x;
    if (gid >= total) return;
    int ksg = gid / 3072;
    int e   = gid % 3072;
    const float* src = T.j[0].src; int k0 = 0, ksrc = 0;
    #pragma unroll
    for (int jj = 0; jj < 22; ++jj){
        int s = T.j[jj].ck;
        if (ksg >= s && ksg < s + T.j[jj].ks){ src = T.j[jj].src; k0 = (ksg - s)*32; ksrc = T.j[jj].ksrc; }
    }
    int nt   = e >> 9;
    int rem  = e & 511;
    int lane = rem >> 3;
    int jx   = rem & 7;
    int k = k0 + ((lane >> 4) << 3) + jx;
    int f = nt*16 + (lane & 15);
    float v = (k < ksrc) ? src[(size_t)k*HDIM + f] : 0.0f;
    dst[gid] = f2bf(v);
}

// swizzle of combined [W1s | W1r] (96 x 192) per layer for the SR GEMM
__global__ __launch_bounds__(256) void swizzle2_kernel(const float* __restrict__ msg_w1,
                                                       short* __restrict__ dst, int total){
    int gid = blockIdx.x*256 + threadIdx.x;
    if (gid >= total) return;
    int layer = gid / 18432;
    int e     = gid % 18432;
    int ksg = e / 6144;
    int rem = e % 6144;
    int nt   = rem >> 9;
    int r2   = rem & 511;
    int lane = r2 >> 3;
    int jx   = r2 & 7;
    int k = ksg*32 + ((lane >> 4) << 3) + jx;     // 0..95
    int f = nt*16 + (lane & 15);                  // 0..191
    int row = (f < 96) ? k : (96 + k);
    int col = (f < 96) ? f : (f - 96);
    dst[gid] = f2bf(msg_w1[(size_t)layer*193*96 + (size_t)row*96 + col]);
}

// ---------------- edge sorting (counting sort by rec) ----------------
__global__ __launch_bounds__(256) void hist_kernel(const int* __restrict__ rec, int* __restrict__ deg, int E){
    int e = blockIdx.x*256 + threadIdx.x;
    if (e < E) atomicAdd(&deg[rec[e]], 1);
}

__global__ __launch_bounds__(256) void scan_part(const int* __restrict__ deg, int* __restrict__ part, int N){
    __shared__ int red[256];
    const int t = threadIdx.x;
    int base = blockIdx.x*1024;
    int s = 0;
    #pragma unroll
    for (int j=0;j<4;j++){ int i = base + j*256 + t; s += (i<N)?deg[i]:0; }
    red[t]=s; __syncthreads();
    #pragma unroll
    for (int off=128; off>0; off>>=1){ if (t<off) red[t]+=red[t+off]; __syncthreads(); }
    if (t==0) part[blockIdx.x]=red[0];
}
__global__ __launch_bounds__(256) void scan_top(int* __restrict__ part, int nb){
    __shared__ int buf[256];
    const int t = threadIdx.x;
    int v = (t < nb) ? part[t] : 0;
    buf[t] = v;
    __syncthreads();
    #pragma unroll
    for (int off=1; off<256; off<<=1){
        int u = (t>=off)?buf[t-off]:0;
        __syncthreads();
        buf[t] += u;
        __syncthreads();
    }
    if (t < nb) part[t] = buf[t] - v;
}
__global__ __launch_bounds__(256) void scan_final(const int* __restrict__ deg, const int* __restrict__ part,
                                                  int* __restrict__ cur, int N){
    __shared__ int tsum[256];
    const int t = threadIdx.x;
    int i0 = blockIdx.x*1024 + t*4;
    int a0 = (i0+0<N)?deg[i0+0]:0;
    int a1 = (i0+1<N)?deg[i0+1]:0;
    int a2 = (i0+2<N)?deg[i0+2]:0;
    int a3 = (i0+3<N)?deg[i0+3]:0;
    int s = a0+a1+a2+a3;
    tsum[t]=s; __syncthreads();
    #pragma unroll
    for (int off=1; off<256; off<<=1){
        int u = (t>=off)?tsum[t-off]:0;
        __syncthreads();
        tsum[t]+=u;
        __syncthreads();
    }
    int excl = tsum[t]-s + part[blockIdx.x];
    if (i0+0<N) cur[i0+0]=excl;
    if (i0+1<N) cur[i0+1]=excl+a0;
    if (i0+2<N) cur[i0+2]=excl+a0+a1;
    if (i0+3<N) cur[i0+3]=excl+a0+a1+a2;
}

__global__ __launch_bounds__(256) void scatter_kernel(
    const int* __restrict__ send, const int* __restrict__ rec, const float* __restrict__ pos,
    int* __restrict__ cur, int* __restrict__ send_s, int* __restrict__ rec_s,
    float* __restrict__ dist_s, int E)
{
    int e = blockIdx.x*256 + threadIdx.x;
    if (e >= E) return;
    int s = send[e], r = rec[e];
    int p = atomicAdd(&cur[r], 1);
    send_s[p] = s;
    rec_s[p]  = r;
    float dx = pos[3*s]   - pos[3*r];
    float dy = pos[3*s+1] - pos[3*r+1];
    float dz = pos[3*s+2] - pos[3*r+2];
    dist_s[p] = sqrtf(dx*dx + dy*dy + dz*dz);
}

// ---------------- edge: gather SR, silu into B-frags, GEMM2, segment-reduce ----------------
// Edges sorted by rec => interior segments are complete runs: plain stores.
// Only first/last segment of a block can straddle block boundaries: atomics.
__global__ __launch_bounds__(256,5) void edge_kernel(
    const short* __restrict__ SR,
    const int* __restrict__ send_s, const int* __restrict__ rec_s, const float* __restrict__ dist_s,
    const float* __restrict__ w1r192,
    const short* __restrict__ w2sw, const float* __restrict__ b2,
    float* __restrict__ aggr, int E)
{
    __shared__ short msgS[TILE*104];     // bf16 messages, 26624 B
    __shared__ int   recS[TILE];
    __shared__ int   startIdxS[TILE+1];
    __shared__ int   wcntS[2];
    const int t  = threadIdx.x;
    const int e0 = blockIdx.x * TILE;

    if (t < TILE) {
        int e = e0 + t; if (e >= E) e = E - 1;
        recS[t] = rec_s[e];
    }
    __syncthreads();

    // segment table via ballot
    bool flag = false;
    if (t < TILE) flag = (t == 0) || (recS[t] != recS[t-1]);
    unsigned long long bmask = __ballot(flag ? 1 : 0);
    int pre = __popcll(bmask & ((1ull << (t & 63)) - 1ull));
    if (t < TILE && (t & 63) == 0) wcntS[t >> 6] = __popcll(bmask);
    __syncthreads();
    const int nseg = wcntS[0] + wcntS[1];
    if (flag) startIdxS[pre + ((t >> 6) ? wcntS[0] : 0)] = t;
    if (t == 0) startIdxS[nseg] = TILE;
    // visible after the pre-segsum barrier

    // block-boundary segment detection (scalar, L1-cached)
    const bool firstB = (e0 > 0) && (rec_s[e0-1] == recS[0]);
    const bool lastB  = (e0 + TILE < E) && (rec_s[e0 + TILE] == recS[TILE-1]);

    const int lane = t & 63;
    const int wv   = t >> 6;
    const int e_lo = wv * 32;
    const int col  = lane & 15;
    const int quad = lane >> 4;
    const int frow = quad * 4;
    const float4v fzero = {0.f,0.f,0.f,0.f};

    // build this lane's own B-fragments: t1[e][f], f = ks*32 + quad*8 + j
    short8 frag[2][3];
    #pragma unroll
    for (int et=0; et<2; ++et){
        int ei = e_lo + et*16 + col;
        int ec = e0 + ei; if (ec >= E) ec = E - 1;
        int se = send_s[ec];
        int re = recS[ei];
        float d = dist_s[ec];
        #pragma unroll
        for (int ks=0; ks<3; ++ks){
            int f0 = ks*32 + quad*8;
            short8 S8 = *(const short8*)(SR + (size_t)se*192 + f0);
            short8 R8 = *(const short8*)(SR + (size_t)re*192 + 96 + f0);
            float4v wa = *(const float4v*)(w1r192 + f0);
            float4v wb = *(const float4v*)(w1r192 + f0 + 4);
            short8 fr;
            #pragma unroll
            for (int j=0;j<8;j++){
                float w = (j<4) ? wa[j] : wb[j-4];
                float v = bf2f(S8[j]) + bf2f(R8[j]) + d*w;
                fr[j] = f2bf(silu_f(v));
            }
            frag[et][ks] = fr;
        }
    }

    float4v acc2[2][6];
    #pragma unroll
    for (int i=0;i<2;i++)
      #pragma unroll
      for (int n=0;n<6;n++) acc2[i][n] = fzero;

    const short8* w2f = (const short8*)w2sw;
    #pragma unroll
    for (int ks = 0; ks < 3; ++ks) {
        #pragma unroll
        for (int mt = 0; mt < 6; ++mt) {
            short8 a = w2f[(ks*6+mt)*64 + lane];
            acc2[0][mt] = __builtin_amdgcn_mfma_f32_16x16x32_bf16(a, frag[0][ks], acc2[0][mt], 0, 0, 0);
            acc2[1][mt] = __builtin_amdgcn_mfma_f32_16x16x32_bf16(a, frag[1][ks], acc2[1][mt], 0, 0, 0);
        }
    }
    float4v b2v[6];
    #pragma unroll
    for (int mt=0; mt<6; ++mt) b2v[mt] = *(const float4v*)(b2 + mt*16 + frow);

    #pragma unroll
    for (int et=0; et<2; ++et){
        int e = e_lo + et*16 + col;
        bool valid = (e0 + e) < E;
        #pragma unroll
        for (int mt=0; mt<6; ++mt){
            short4v sv;
            #pragma unroll
            for (int r=0;r<4;r++){
                float u = silu_f(acc2[et][mt][r] + b2v[mt][r]);
                sv[r] = f2bf(valid ? u : 0.0f);
            }
            *(short4v*)(msgS + e*104 + mt*16 + frow) = sv;
        }
    }
    __syncthreads();

    // segment-sum: item = (segment, 8-col group); interior -> plain float4 stores,
    // boundary (straddling) segments -> atomicAdd
    const int items = nseg * 12;
    for (int item = t; item < items; item += 256){
        int s  = item / 12;
        int fg = item - s*12;
        int r0 = startIdxS[s], r1 = startIdxS[s+1];
        float sum[8] = {0.f,0.f,0.f,0.f,0.f,0.f,0.f,0.f};
        for (int r = r0; r < r1; ++r){
            short8 v8 = *(const short8*)(msgS + r*104 + fg*8);
            #pragma unroll
            for (int j=0;j<8;j++) sum[j] += bf2f(v8[j]);
        }
        float* dstp = aggr + (size_t)recS[r0]*HDIM + fg*8;
        bool bnd = (s == 0 && firstB) || (s == nseg-1 && lastB);
        if (bnd) {
            #pragma unroll
            for (int j=0;j<8;j++) atomicAdd(dstp+j, sum[j]);
        } else {
            float4v lo = {sum[0], sum[1], sum[2], sum[3]};
            float4v hi = {sum[4], sum[5], sum[6], sum[7]};
            *(float4v*)(dstp)     = lo;
            *(float4v*)(dstp + 4) = hi;
        }
    }
}

// ---------------- node update: h += MLP([h, aggr]); re-zero aggr; optional SR for next layer ----------------
__global__ __launch_bounds__(256,3) void update_kernel(
    float* __restrict__ h, short* __restrict__ hbf, float* __restrict__ aggr,
    const short* __restrict__ w1sw, const float* __restrict__ b1,
    const short* __restrict__ w2sw, const float* __restrict__ b2,
    const short* __restrict__ w1sr_next, const float* __restrict__ msgb1_next,
    short* __restrict__ SR, int N)
{
    __shared__ short stateS[TILE*200];
    const int t  = threadIdx.x;
    const int n0 = blockIdx.x * TILE;

    #pragma unroll
    for (int it = 0; it < 12; ++it) {
        int q = it*256 + t;    // 128 rows * 24 chunks
        int c = q % 24;
        int i = q / 24;
        int node = n0 + i;
        if (c < 12) {
            uint4v v = {0u,0u,0u,0u};
            if (node < N) v = *(const uint4v*)(hbf + (size_t)node*HDIM + c*8);
            *(uint4v*)(stateS + i*200 + c*8) = v;
        } else {
            int cc = c - 12;
            short8 s8 = {0,0,0,0,0,0,0,0};
            if (node < N) {
                float4v a0 = *(const float4v*)(aggr + (size_t)node*HDIM + cc*8);
                float4v a1 = *(const float4v*)(aggr + (size_t)node*HDIM + cc*8 + 4);
                s8[0]=f2bf(a0[0]); s8[1]=f2bf(a0[1]); s8[2]=f2bf(a0[2]); s8[3]=f2bf(a0[3]);
                s8[4]=f2bf(a1[0]); s8[5]=f2bf(a1[1]); s8[6]=f2bf(a1[2]); s8[7]=f2bf(a1[3]);
            }
            *(short8*)(stateS + i*200 + HDIM + cc*8) = s8;
        }
    }
    __syncthreads();

    const int lane = t & 63;
    const int wv   = t >> 6;
    const int e_lo = wv * 32;
    const int col  = lane & 15;
    const int quad = lane >> 4;
    const int koff = quad * 8;
    const int frow = quad * 4;
    const float4v fzero = {0.f,0.f,0.f,0.f};

    float4v acc[2][6];
    #pragma unroll
    for (int i=0;i<2;i++)
      #pragma unroll
      for (int n=0;n<6;n++) acc[i][n] = fzero;

    const short8* w1f = (const short8*)w1sw;
    #pragma unroll
    for (int ks = 0; ks < 6; ++ks) {
        short8 bb0 = *(const short8*)(stateS + (e_lo+col)*200    + ks*32 + koff);
        short8 bb1 = *(const short8*)(stateS + (e_lo+16+col)*200 + ks*32 + koff);
        #pragma unroll
        for (int mt = 0; mt < 6; ++mt) {
            short8 a = w1f[(ks*6+mt)*64 + lane];
            acc[0][mt] = __builtin_amdgcn_mfma_f32_16x16x32_bf16(a, bb0, acc[0][mt], 0, 0, 0);
            acc[1][mt] = __builtin_amdgcn_mfma_f32_16x16x32_bf16(a, bb1, acc[1][mt], 0, 0, 0);
        }
    }
    float4v b1v[6];
    #pragma unroll
    for (int mt=0; mt<6; ++mt) b1v[mt] = *(const float4v*)(b1 + mt*16 + frow);
    __syncthreads();

    short* t1S = stateS;   // stride 104
    #pragma unroll
    for (int et=0; et<2; ++et){
        int e = e_lo + et*16 + col;
        #pragma unroll
        for (int mt=0; mt<6; ++mt){
            short4v sv;
            #pragma unroll
            for (int r=0;r<4;r++) sv[r] = f2bf(silu_f(acc[et][mt][r] + b1v[mt][r]));
            *(short4v*)(t1S + e*104 + mt*16 + frow) = sv;
        }
    }
    __syncthreads();

    float4v acc2[2][6];
    #pragma unroll
    for (int i=0;i<2;i++)
      #pragma unroll
      for (int n=0;n<6;n++) acc2[i][n] = fzero;

    const short8* w2f = (const short8*)w2sw;
    #pragma unroll
    for (int ks = 0; ks < 3; ++ks) {
        short8 bb0 = *(const short8*)(t1S + (e_lo+col)*104    + ks*32 + koff);
        short8 bb1 = *(const short8*)(t1S + (e_lo+16+col)*104 + ks*32 + koff);
        #pragma unroll
        for (int mt = 0; mt < 6; ++mt) {
            short8 a = w2f[(ks*6+mt)*64 + lane];
            acc2[0][mt] = __builtin_amdgcn_mfma_f32_16x16x32_bf16(a, bb0, acc2[0][mt], 0, 0, 0);
            acc2[1][mt] = __builtin_amdgcn_mfma_f32_16x16x32_bf16(a, bb1, acc2[1][mt], 0, 0, 0);
        }
    }
    float4v b2v[6];
    #pragma unroll
    for (int mt=0; mt<6; ++mt) b2v[mt] = *(const float4v*)(b2 + mt*16 + frow);
    __syncthreads();   // all GEMM2 t1 reads done; we will overwrite with new-h bf16

    #pragma unroll
    for (int et=0; et<2; ++et){
        int erow = e_lo + et*16 + col;
        int node = n0 + erow;
        bool valid = node < N;
        size_t base = (size_t)node*HDIM;
        #pragma unroll
        for (int mt=0; mt<6; ++mt){
            int f0 = mt*16 + frow;
            float4v old = valid ? *(const float4v*)(h + base + f0) : fzero;
            float4v o;
            #pragma unroll
            for (int r=0;r<4;r++) o[r] = old[r] + acc2[et][mt][r] + b2v[mt][r];
            short4v sv = {f2bf(o[0]), f2bf(o[1]), f2bf(o[2]), f2bf(o[3])};
            if (valid) {
                *(float4v*)(h + base + f0) = o;
                *(short4v*)(hbf + base + f0) = sv;
                *(float4v*)(aggr + base + f0) = fzero;
            }
            *(short4v*)(stateS + erow*104 + f0) = sv;   // new h, bf16, stride 104
        }
    }

    if (w1sr_next) {   // produce SR for the next layer's edge kernel
        __syncthreads();
        float4v accS[2][12];
        #pragma unroll
        for (int i=0;i<2;i++)
          #pragma unroll
          for (int n=0;n<12;n++) accS[i][n] = fzero;

        const short8* wsf = (const short8*)w1sr_next;
        #pragma unroll
        for (int ks = 0; ks < 3; ++ks) {
            short8 bb0 = *(const short8*)(stateS + (e_lo+col)*104    + ks*32 + koff);
            short8 bb1 = *(const short8*)(stateS + (e_lo+16+col)*104 + ks*32 + koff);
            #pragma unroll
            for (int mt = 0; mt < 12; ++mt) {
                short8 a = wsf[(ks*12+mt)*64 + lane];
                accS[0][mt] = __builtin_amdgcn_mfma_f32_16x16x32_bf16(a, bb0, accS[0][mt], 0, 0, 0);
                accS[1][mt] = __builtin_amdgcn_mfma_f32_16x16x32_bf16(a, bb1, accS[1][mt], 0, 0, 0);
            }
        }
        float4v bnv[6];
        #pragma unroll
        for (int mt=0; mt<6; ++mt) bnv[mt] = *(const float4v*)(msgb1_next + mt*16 + frow);

        #pragma unroll
        for (int et=0; et<2; ++et){
            int node = n0 + e_lo + et*16 + col;
            if (node < N) {
                size_t sbase = (size_t)node*192;
                #pragma unroll
                for (int mt=0; mt<12; ++mt){
                    float4v o = accS[et][mt];
                    if (mt < 6) { o[0]+=bnv[mt][0]; o[1]+=bnv[mt][1]; o[2]+=bnv[mt][2]; o[3]+=bnv[mt][3]; }
                    short4v sv = {f2bf(o[0]), f2bf(o[1]), f2bf(o[2]), f2bf(o[3])};
                    *(short4v*)(SR + sbase + mt*16 + frow) = sv;
                }
            }
        }
    }
}

// ---------------- embed: h = silu([x|pe] W1 + b1) W2 + b2 ; + SR for layer 0 ----------------
__global__ __launch_bounds__(256,3) void embed_kernel(
    const float* __restrict__ x, const float* __restrict__ pe,
    const short* __restrict__ w1sw, const float* __restrict__ b1,
    const short* __restrict__ w2sw, const float* __restrict__ b2,
    float* __restrict__ h, short* __restrict__ hbf,
    const short* __restrict__ w1sr0, const float* __restrict__ msgb1_0,
    short* __restrict__ SR, int N)
{
    __shared__ short stateS[TILE*72];
    __shared__ short t1S[TILE*104];
    const int t  = threadIdx.x;
    const int n0 = blockIdx.x * TILE;

    if (t < TILE) {
        int node = n0 + t;
        short* row = stateS + t*72;
        if (node < N) {
            #pragma unroll
            for (int j=0;j<11;j++) row[j]    = f2bf(x[(size_t)node*11 + j]);
            #pragma unroll
            for (int j=0;j<24;j++) row[11+j] = f2bf(pe[(size_t)node*24 + j]);
            #pragma unroll
            for (int j=35;j<64;j++) row[j] = 0;
        } else {
            #pragma unroll
            for (int j=0;j<64;j++) row[j] = 0;
        }
    }
    __syncthreads();

    const int lane = t & 63;
    const int wv   = t >> 6;
    const int e_lo = wv * 32;
    const int col  = lane & 15;
    const int quad = lane >> 4;
    const int koff = quad * 8;
    const int frow = quad * 4;
    const float4v fzero = {0.f,0.f,0.f,0.f};

    float4v acc[2][6];
    #pragma unroll
    for (int i=0;i<2;i++)
      #pragma unroll
      for (int n=0;n<6;n++) acc[i][n] = fzero;

    const short8* w1f = (const short8*)w1sw;
    #pragma unroll
    for (int ks = 0; ks < 2; ++ks) {
        short8 bb0 = *(const short8*)(stateS + (e_lo+col)*72    + ks*32 + koff);
        short8 bb1 = *(const short8*)(stateS + (e_lo+16+col)*72 + ks*32 + koff);
        #pragma unroll
        for (int mt = 0; mt < 6; ++mt) {
            short8 a = w1f[(ks*6+mt)*64 + lane];
            acc[0][mt] = __builtin_amdgcn_mfma_f32_16x16x32_bf16(a, bb0, acc[0][mt], 0, 0, 0);
            acc[1][mt] = __builtin_amdgcn_mfma_f32_16x16x32_bf16(a, bb1, acc[1][mt], 0, 0, 0);
        }
    }
    float4v b1v[6];
    #pragma unroll
    for (int mt=0; mt<6; ++mt) b1v[mt] = *(const float4v*)(b1 + mt*16 + frow);

    #pragma unroll
    for (int et=0; et<2; ++et){
        int e = e_lo + et*16 + col;
        #pragma unroll
        for (int mt=0; mt<6; ++mt){
            short4v sv;
            #pragma unroll
            for (int r=0;r<4;r++) sv[r] = f2bf(silu_f(acc[et][mt][r] + b1v[mt][r]));
            *(short4v*)(t1S + e*104 + mt*16 + frow) = sv;
        }
    }
    __syncthreads();

    float4v acc2[2][6];
    #pragma unroll
    for (int i=0;i<2;i++)
      #pragma unroll
      for (int n=0;n<6;n++) acc2[i][n] = fzero;

    const short8* w2f = (const short8*)w2sw;
    #pragma unroll
    for (int ks = 0; ks < 3; ++ks) {
        short8 bb0 = *(const short8*)(t1S + (e_lo+col)*104    + ks*32 + koff);
        short8 bb1 = *(const short8*)(t1S + (e_lo+16+col)*104 + ks*32 + koff);
        #pragma unroll
        for (int mt = 0; mt < 6; ++mt) {
            short8 a = w2f[(ks*6+mt)*64 + lane];
            acc2[0][mt] = __builtin_amdgcn_mfma_f32_16x16x32_bf16(a, bb0, acc2[0][mt], 0, 0, 0);
            acc2[1][mt] = __builtin_amdgcn_mfma_f32_16x16x32_bf16(a, bb1, acc2[1][mt], 0, 0, 0);
        }
    }
    float4v b2v[6];
    #pragma unroll
    for (int mt=0; mt<6; ++mt) b2v[mt] = *(const float4v*)(b2 + mt*16 + frow);
    __syncthreads();   // GEMM2 t1 reads done; reuse t1S for new-h bf16

    #pragma unroll
    for (int et=0; et<2; ++et){
        int erow = e_lo + et*16 + col;
        int node = n0 + erow;
        bool valid = node < N;
        size_t base = (size_t)node*HDIM;
        #pragma unroll
        for (int mt=0; mt<6; ++mt){
            int f0 = mt*16 + frow;
            float4v o;
            #pragma unroll
            for (int r=0;r<4;r++) o[r] = acc2[et][mt][r] + b2v[mt][r];
            short4v sv = {f2bf(o[0]), f2bf(o[1]), f2bf(o[2]), f2bf(o[3])};
            if (valid) {
                *(float4v*)(h + base + f0) = o;
                *(short4v*)(hbf + base + f0) = sv;
            }
            *(short4v*)(t1S + erow*104 + f0) = sv;
        }
    }
    __syncthreads();

    // SR for layer 0
    float4v accS[2][12];
    #pragma unroll
    for (int i=0;i<2;i++)
      #pragma unroll
      for (int n=0;n<12;n++) accS[i][n] = fzero;

    const short8* wsf = (const short8*)w1sr0;
    #pragma unroll
    for (int ks = 0; ks < 3; ++ks) {
        short8 bb0 = *(const short8*)(t1S + (e_lo+col)*104    + ks*32 + koff);
        short8 bb1 = *(const short8*)(t1S + (e_lo+16+col)*104 + ks*32 + koff);
        #pragma unroll
        for (int mt = 0; mt < 12; ++mt) {
            short8 a = wsf[(ks*12+mt)*64 + lane];
            accS[0][mt] = __builtin_amdgcn_mfma_f32_16x16x32_bf16(a, bb0, accS[0][mt], 0, 0, 0);
            accS[1][mt] = __builtin_amdgcn_mfma_f32_16x16x32_bf16(a, bb1, accS[1][mt], 0, 0, 0);
        }
    }
    float4v bnv[6];
    #pragma unroll
    for (int mt=0; mt<6; ++mt) bnv[mt] = *(const float4v*)(msgb1_0 + mt*16 + frow);

    #pragma unroll
    for (int et=0; et<2; ++et){
        int node = n0 + e_lo + et*16 + col;
        if (node < N) {
            size_t sbase = (size_t)node*192;
            #pragma unroll
            for (int mt=0; mt<12; ++mt){
                float4v o = accS[et][mt];
                if (mt < 6) { o[0]+=bnv[mt][0]; o[1]+=bnv[mt][1]; o[2]+=bnv[mt][2]; o[3]+=bnv[mt][3]; }
                short4v sv = {f2bf(o[0]), f2bf(o[1]), f2bf(o[2]), f2bf(o[3])};
                *(short4v*)(SR + sbase + mt*16 + frow) = sv;
            }
        }
    }
}

// ---------------- pre-MLP + pooling, segment-reduced over sorted batch ----------------
__global__ __launch_bounds__(256,2) void prepool_kernel(
    const short* __restrict__ hbf,
    const short* __restrict__ w1sw, const float* __restrict__ b1,
    const short* __restrict__ w2sw, const float* __restrict__ b2,
    const int* __restrict__ batch, float* __restrict__ pooled, int N)
{
    __shared__ short bufS[TILE*104*2];   // 53248 B: state | t1 ; later msg fp32 (51200 B)
    __shared__ int   batchS[TILE];
    __shared__ int   startIdxS[TILE+1];
    __shared__ int   wcntS[2];
    short* stateS = bufS;                 // stride 104
    short* t1S    = bufS + TILE*104;      // stride 104
    float* msgS   = (float*)bufS;         // stride 100
    const int t  = threadIdx.x;
    const int n0 = blockIdx.x * TILE;

    #pragma unroll
    for (int it = 0; it < 6; ++it) {
        int q = it*256 + t;
        int c = q % 12;
        int i = q / 12;
        int node = n0 + i;
        uint4v v = {0u,0u,0u,0u};
        if (node < N) v = *(const uint4v*)(hbf + (size_t)node*HDIM + c*8);
        *(uint4v*)(stateS + i*104 + c*8) = v;
    }
    if (t < TILE) {
        int node = n0 + t;
        batchS[t] = batch[node < N ? node : N-1];
    }
    __syncthreads();

    bool flag = false;
    if (t < TILE) flag = (t == 0) || (batchS[t] != batchS[t-1]);
    unsigned long long bmask = __ballot(flag ? 1 : 0);
    int pre = __popcll(bmask & ((1ull << (t & 63)) - 1ull));
    if (t < TILE && (t & 63) == 0) wcntS[t >> 6] = __popcll(bmask);

    const int lane = t & 63;
    const int wv   = t >> 6;
    const int e_lo = wv * 32;
    const int col  = lane & 15;
    const int quad = lane >> 4;
    const int koff = quad * 8;
    const int frow = quad * 4;
    const float4v fzero = {0.f,0.f,0.f,0.f};

    float4v acc[2][6];
    #pragma unroll
    for (int i=0;i<2;i++)
      #pragma unroll
      for (int n=0;n<6;n++) acc[i][n] = fzero;

    const short8* w1f = (const short8*)w1sw;
    #pragma unroll
    for (int ks = 0; ks < 3; ++ks) {
        short8 bb0 = *(const short8*)(stateS + (e_lo+col)*104    + ks*32 + koff);
        short8 bb1 = *(const short8*)(stateS + (e_lo+16+col)*104 + ks*32 + koff);
        #pragma unroll
        for (int mt = 0; mt < 6; ++mt) {
            short8 a = w1f[(ks*6+mt)*64 + lane];
            acc[0][mt] = __builtin_amdgcn_mfma_f32_16x16x32_bf16(a, bb0, acc[0][mt], 0, 0, 0);
            acc[1][mt] = __builtin_amdgcn_mfma_f32_16x16x32_bf16(a, bb1, acc[1][mt], 0, 0, 0);
        }
    }
    float4v b1v[6];
    #pragma unroll
    for (int mt=0; mt<6; ++mt) b1v[mt] = *(const float4v*)(b1 + mt*16 + frow);

    #pragma unroll
    for (int et=0; et<2; ++et){
        int e = e_lo + et*16 + col;
        #pragma unroll
        for (int mt=0; mt<6; ++mt){
            short4v sv;
            #pragma unroll
            for (int r=0;r<4;r++) sv[r] = f2bf(silu_f(acc[et][mt][r] + b1v[mt][r]));
            *(short4v*)(t1S + e*104 + mt*16 + frow) = sv;
        }
    }
    __syncthreads();
    const int nseg = wcntS[0] + wcntS[1];
    if (flag) startIdxS[pre + ((t >> 6) ? wcntS[0] : 0)] = t;
    if (t == 0) startIdxS[nseg] = TILE;

    float4v acc2[2][6];
    #pragma unroll
    for (int i=0;i<2;i++)
      #pragma unroll
      for (int n=0;n<6;n++) acc2[i][n] = fzero;

    const short8* w2f = (const short8*)w2sw;
    #pragma unroll
    for (int ks = 0; ks < 3; ++ks) {
        short8 bb0 = *(const short8*)(t1S + (e_lo+col)*104    + ks*32 + koff);
        short8 bb1 = *(const short8*)(t1S + (e_lo+16+col)*104 + ks*32 + koff);
        #pragma unroll
        for (int mt = 0; mt < 6; ++mt) {
            short8 a = w2f[(ks*6+mt)*64 + lane];
            acc2[0][mt] = __builtin_amdgcn_mfma_f32_16x16x32_bf16(a, bb0, acc2[0][mt], 0, 0, 0);
            acc2[1][mt] = __builtin_amdgcn_mfma_f32_16x16x32_bf16(a, bb1, acc2[1][mt], 0, 0, 0);
        }
    }
    float4v b2v[6];
    #pragma unroll
    for (int mt=0; mt<6; ++mt) b2v[mt] = *(const float4v*)(b2 + mt*16 + frow);
    __syncthreads();   // t1 reads done; msg overwrites buf

    #pragma unroll
    for (int et=0; et<2; ++et){
        int e = e_lo + et*16 + col;
        bool valid = (n0 + e) < N;
        #pragma unroll
        for (int mt=0; mt<6; ++mt){
            float4v v;
            #pragma unroll
            for (int r=0;r<4;r++){
                float u = acc2[et][mt][r] + b2v[mt][r];
                v[r] = valid ? u : 0.0f;
            }
            *(float4v*)(msgS + e*100 + mt*16 + frow) = v;
        }
    }
    __syncthreads();

    const int items = nseg * 24;
    for (int item = t; item < items; item += 256){
        int s  = item / 24;
        int fg = item - s*24;
        int r0 = startIdxS[s], r1 = startIdxS[s+1];
        float4v sum = fzero;
        for (int r = r0; r < r1; ++r) sum += *(const float4v*)(msgS + r*100 + fg*4);
        float* dstp = pooled + (size_t)batchS[r0]*HDIM + fg*4;
        atomicAdd(dstp+0, sum[0]);
        atomicAdd(dstp+1, sum[1]);
        atomicAdd(dstp+2, sum[2]);
        atomicAdd(dstp+3, sum[3]);
    }
}

// ---------------- readout ----------------
__global__ __launch_bounds__(128) void readout_kernel(
    const float* __restrict__ pooled,
    const float* __restrict__ w1, const float* __restrict__ b1,
    const float* __restrict__ w2, const float* __restrict__ b2,
    float* __restrict__ out)
{
    __shared__ float red[128];
    const int g = blockIdx.x;
    const int t = threadIdx.x;
    float p = 0.0f;
    if (t < HDIM) {
        float acc = b1[t];
        for (int k = 0; k < HDIM; ++k)
            acc += pooled[(size_t)g*HDIM + k] * w1[(size_t)k*HDIM + t];
        acc = silu_f(acc);
        p = acc * w2[t];
    }
    red[t] = p;
    __syncthreads();
    for (int s = 64; s > 0; s >>= 1) {
        if (t < s) red[t] += red[t + s];
        __syncthreads();
    }
    if (t == 0) out[g] = red[0] + b2[0];
}

extern "C" void kernel_launch(void* const* d_in, const int* in_sizes, int n_in,
                              void* d_out, int out_size, void* d_ws, size_t ws_size,
                              hipStream_t stream)
{
    const float* x        = (const float*)d_in[0];
    const float* pos      = (const float*)d_in[1];
    const float* pe       = (const float*)d_in[2];
    const int*   ei       = (const int*)d_in[3];
    const int*   batch    = (const int*)d_in[4];
    const float* embed_w1 = (const float*)d_in[5];
    const float* embed_b1 = (const float*)d_in[6];
    const float* embed_w2 = (const float*)d_in[7];
    const float* embed_b2 = (const float*)d_in[8];
    const float* msg_w1   = (const float*)d_in[9];
    const float* msg_b1   = (const float*)d_in[10];
    const float* msg_w2   = (const float*)d_in[11];
    const float* msg_b2   = (const float*)d_in[12];
    const float* upd_w1   = (const float*)d_in[13];
    const float* upd_b1   = (const float*)d_in[14];
    const float* upd_w2   = (const float*)d_in[15];
    const float* upd_b2   = (const float*)d_in[16];
    const float* pre_w1   = (const float*)d_in[17];
    const float* pre_b1   = (const float*)d_in[18];
    const float* pre_w2   = (const float*)d_in[19];
    const float* pre_b2   = (const float*)d_in[20];
    const float* ro_w1    = (const float*)d_in[21];
    const float* ro_b1    = (const float*)d_in[22];
    const float* ro_w2    = (const float*)d_in[23];
    const float* ro_b2    = (const float*)d_in[24];

    const int E = in_sizes[3] / 2;
    const int N = in_sizes[4];
    const int G = out_size;

    char* ws = (char*)d_ws;
    size_t off = 0;
    auto alloc = [&](size_t bytes){ void* p = ws + off; off += (bytes + 255) & ~(size_t)255; return p; };
    float* h      = (float*)alloc((size_t)N*HDIM*4);
    short* hbf    = (short*)alloc((size_t)N*HDIM*2);
    float* aggr   = (float*)alloc((size_t)N*HDIM*4);
    float* pooled = (float*)alloc((size_t)G*HDIM*4);
    short* wsw    = (short*)alloc((size_t)59*3072*2);
    short* w1sr   = (short*)alloc((size_t)4*18432*2);
    short* SR     = (short*)alloc((size_t)N*192*2);
    int*   deg    = (int*)alloc((size_t)N*4);
    int*   cur    = (int*)alloc((size_t)N*4);
    int*   part   = (int*)alloc((size_t)256*4);
    int*   send_s = (int*)alloc((size_t)E*4);
    int*   rec_s  = (int*)alloc((size_t)E*4);
    float* dist_s = (float*)alloc((size_t)E*4);

    hipMemsetAsync(aggr,   0, (size_t)N*HDIM*4, stream);
    hipMemsetAsync(pooled, 0, (size_t)G*HDIM*4, stream);
    hipMemsetAsync(deg,    0, (size_t)N*4, stream);

    SwTable T;
    for (int jj=0;jj<22;jj++){ T.j[jj].src = embed_w1; T.j[jj].ck = 1<<30; T.j[jj].ks = 0; T.j[jj].ksrc = 0; }
    int ck = 0, ji = 0;
    auto add = [&](const float* s, int ks, int ksrc){
        T.j[ji].src = s; T.j[ji].ck = ck; T.j[ji].ks = ks; T.j[ji].ksrc = ksrc;
        ji++; ck += ks;
    };
    add(embed_w1, 2, 35);   // ck 0
    add(embed_w2, 3, 96);   // ck 2
    add(pre_w1,   3, 96);   // ck 5
    add(pre_w2,   3, 96);   // ck 8
    for (int l=0;l<4;l++) add(msg_w2 + (size_t)l*96*96,  3, 96);   // ck 11+3l
    for (int l=0;l<4;l++) add(upd_w1 + (size_t)l*192*96, 6, 192);  // ck 23+6l
    for (int l=0;l<4;l++) add(upd_w2 + (size_t)l*96*96,  3, 96);   // ck 47+3l
    const int total = 59*3072;
    swizzle_kernel<<<(total+255)/256, 256, 0, stream>>>(T, wsw, total);
    const int total2 = 4*18432;
    swizzle2_kernel<<<(total2+255)/256, 256, 0, stream>>>(msg_w1, w1sr, total2);

    const int nbE256 = (E + 255) / 256;
    const int nbScan = (N + 1023) / 1024;
    hist_kernel<<<nbE256, 256, 0, stream>>>(ei + E, deg, E);
    scan_part<<<nbScan, 256, 0, stream>>>(deg, part, N);
    scan_top<<<1, 256, 0, stream>>>(part, nbScan);
    scan_final<<<nbScan, 256, 0, stream>>>(deg, part, cur, N);
    scatter_kernel<<<nbE256, 256, 0, stream>>>(ei, ei + E, pos, cur, send_s, rec_s, dist_s, E);

    const int nbN = (N + TILE - 1) / TILE;
    embed_kernel<<<nbN, 256, 0, stream>>>(x, pe, wsw + 0, embed_b1, wsw + 2*3072, embed_b2,
                                          h, hbf, w1sr, msg_b1, SR, N);

    const int nbE = (E + TILE - 1) / TILE;
    for (int l = 0; l < 4; ++l) {
        edge_kernel<<<nbE, 256, 0, stream>>>(SR, send_s, rec_s, dist_s,
            msg_w1 + (size_t)l*193*96 + (size_t)192*96,
            wsw + (11 + 3*l)*3072, msg_b2 + l*96, aggr, E);
        const short* w1sr_next = (l < 3) ? (w1sr + (size_t)(l+1)*18432) : nullptr;
        const float* msgb1_next = (l < 3) ? (msg_b1 + (l+1)*96) : nullptr;
        update_kernel<<<nbN, 256, 0, stream>>>(h, hbf, aggr,
            wsw + (23 + 6*l)*3072, upd_b1 + l*96,
            wsw + (47 + 3*l)*3072, upd_b2 + l*96,
            w1sr_next, msgb1_next, SR, N);
    }

    prepool_kernel<<<nbN, 256, 0, stream>>>(hbf, wsw + 5*3072, pre_b1, wsw + 8*3072, pre_b2,
                                            batch, pooled, N);
    readout_kernel<<<G, 128, 0, stream>>>(pooled, ro_w1, ro_b1, ro_w2, ro_b2, (float*)d_out);
}